// Round 6
// baseline (530.932 us; speedup 1.0000x reference)
//
#include <hip/hip_runtime.h>

typedef __attribute__((ext_vector_type(8))) short short8;
typedef __attribute__((ext_vector_type(4))) float f32x4;
typedef __attribute__((ext_vector_type(2))) unsigned u32x2;
typedef unsigned short ushort_t;

#define WIMG 1216
#define HIMG 352

__device__ __forceinline__ float sigmoid_(float x){ return 1.f/(1.f+__expf(-x)); }
__device__ __forceinline__ float softplus_(float x){
  return fmaxf(x,0.f) + log1pf(__expf(-fabsf(x)));
}
// exact RNE (weight packing only)
__device__ __forceinline__ ushort_t f2b(float x){
  union { float f; unsigned u; } v; v.f = x;
  unsigned r = v.u + 0x7FFF + ((v.u >> 16) & 1);
  return (ushort_t)(r >> 16);
}
__device__ __forceinline__ ushort_t f2b_fast(float x){
  union { float f; unsigned u; } v; v.f = x;
  return (ushort_t)((v.u + 0x8000u) >> 16);
}
__device__ __forceinline__ unsigned pack_trunc(float a, float b){
  union { float f; unsigned u; } va, vb; va.f = a; vb.f = b;
  return (va.u >> 16) | (vb.u & 0xFFFF0000u);
}
__device__ __forceinline__ float b2f_lo(unsigned u){
  union { unsigned u; float f; } v; v.u = u << 16; return v.f;
}
__device__ __forceinline__ float b2f_hi(unsigned u){
  union { unsigned u; float f; } v; v.u = u & 0xFFFF0000u; return v.f;
}

// ---------- pack weights into fragment order (bf16); also zeroes d_out ----------
// blocks 0..37: [w_in ks0,ks1][i: wz*4, w0*4, w1*4]*3 ; block 38: w_out (16-col zero-padded)
// element: nt=e>>9, lane=(e>>3)&63, j=e&7 ; k=ksbase+(lane>>4)*8+j, n=nt*16+(lane&15)
__global__ void k_pack(const float* __restrict__ w_in, const float* __restrict__ wz,
                       const float* __restrict__ w0, const float* __restrict__ w1,
                       const float* __restrict__ w_out, int outd,
                       ushort_t* __restrict__ pk, float* __restrict__ out0){
  if (out0 && blockIdx.x == 0 && threadIdx.x == 0) out0[0] = 0.f;
  int id = blockIdx.x*256 + threadIdx.x;
  if (id >= 39*4096) return;
  int blk = id >> 12;
  int e = id & 4095;
  float val = 0.f;
  if (blk < 38) {
    int nt = e >> 9, lane = (e >> 3) & 63, j = e & 7;
    int kloc = (lane >> 4)*8 + j;
    int n = nt*16 + (lane & 15);
    if (blk < 2) {
      int k = blk*32 + kloc;
      val = (k < 42) ? w_in[k*128 + n] : 0.f;
    } else {
      int g = blk - 2;
      int i = g / 12, r = g % 12, m = r >> 2, ks = r & 3;
      int k = ks*32 + kloc;
      const float* src = (m==0 ? wz : (m==1 ? w0 : w1)) + i*16384;
      val = src[k*128 + n];
    }
  } else if (e < 2048) {
    int ks = e >> 9, lane = (e >> 3) & 63, j = e & 7;
    int k = ks*32 + (lane >> 4)*8 + j;
    int n = lane & 15;
    val = (n < outd) ? w_out[k*outd + n] : 0.f;
  }
  pk[id] = f2b(val);
}

// ---------- transpose bev (z,c,x,y) fp32 -> vf (z,x,y,c) bf16, 64x64 tiles ----------
__global__ __launch_bounds__(256) void k_transpose(const float* __restrict__ src, ushort_t* __restrict__ dst){
  __shared__ float tile[64][65];
  int zx = blockIdx.z;              // z*128 + x
  int y0 = blockIdx.x * 64;
  int c0 = blockIdx.y * 64;
  int z = zx >> 7, x = zx & 127;
  const float* s = src + (size_t)z*2097152 + (size_t)c0*16384 + (size_t)x*128 + y0;
  int tid = threadIdx.x;
  int r0 = tid >> 4, f4 = tid & 15;
  #pragma unroll
  for (int it = 0; it < 4; ++it) {
    int c = it*16 + r0;
    f32x4 v = __builtin_nontemporal_load((const f32x4*)(s + (size_t)c*16384 + f4*4));
    tile[c][f4*4+0]=v.x; tile[c][f4*4+1]=v.y; tile[c][f4*4+2]=v.z; tile[c][f4*4+3]=v.w;
  }
  __syncthreads();
  ushort_t* d = dst + ((size_t)zx*128 + y0)*128 + c0;
  #pragma unroll
  for (int it = 0; it < 4; ++it) {
    int y = it*16 + r0;
    float a0 = tile[f4*4+0][y], a1 = tile[f4*4+1][y];
    float a2 = tile[f4*4+2][y], a3 = tile[f4*4+3][y];
    u32x2 o; o.x = pack_trunc(a0,a1); o.y = pack_trunc(a2,a3);
    __builtin_nontemporal_store(o, (u32x2*)(d + (size_t)y*128 + f4*4));
  }
}

// ---------- fragment GEMM: wave owns 64 out-channels (chalf) x 32 points (phalf) ----------
// acts in LDS in B-fragment order: tile T=(k>>5)*4+(p>>4), addr = T*512 + lane*8 ushorts
template<int KS>
__device__ __forceinline__ void gemm_frag(const ushort_t* lds,
                                          const ushort_t* __restrict__ pkW,
                                          f32x4 acc[4][2], int chalf, int phalf, int lane)
{
  #pragma unroll
  for (int ks = 0; ks < KS; ++ks) {
    short8 b[2];
    #pragma unroll
    for (int ntL = 0; ntL < 2; ++ntL)
      b[ntL] = *(const short8*)(lds + (ks*4 + phalf*2 + ntL)*512 + lane*8);
    #pragma unroll
    for (int i = 0; i < 4; ++i) {
      short8 w = *(const short8*)(pkW + (size_t)((ks*8 + chalf*4 + i)*64 + lane)*8);
      #pragma unroll
      for (int ntL = 0; ntL < 2; ++ntL)
        acc[i][ntL] = __builtin_amdgcn_mfma_f32_16x16x32_bf16(w, b[ntL], acc[i][ntL], 0,0,0);
    }
  }
}

// lane holds channels c..c+3 (k-dim) of one point -> ds_write_b64 into fragment order
__device__ __forceinline__ void store_reluF(ushort_t* buf, const f32x4 acc[4][2],
                                            int chalf, int phalf, int lane){
  int l15 = lane & 15, quad = lane >> 4;
  #pragma unroll
  for (int i = 0; i < 4; ++i) {
    int c = chalf*64 + i*16 + quad*4;
    int ksp = c >> 5, k3 = (c >> 3) & 3, jj = c & 7;
    #pragma unroll
    for (int ntL = 0; ntL < 2; ++ntL) {
      int nt = phalf*2 + ntL;
      uint2 o;
      o.x = pack_trunc(fmaxf(acc[i][ntL][0],0.f), fmaxf(acc[i][ntL][1],0.f));
      o.y = pack_trunc(fmaxf(acc[i][ntL][2],0.f), fmaxf(acc[i][ntL][3],0.f));
      *(uint2*)(buf + (ksp*4 + nt)*512 + (k3*16 + l15)*8 + jj) = o;
    }
  }
}

// ---------- fused: OUTD=2 gauss (rayinit + MLP + sort), OUTD=4 main (MLP) ----------
template<int OUTD>
__global__ __launch_bounds__(256, 4)
void k_fused(const ushort_t* __restrict__ vfh, const float* __restrict__ vf0, int mode,
             const float* __restrict__ camK, const int* __restrict__ pix,
             const float* __restrict__ noise,
             float* __restrict__ unit, float* __restrict__ viewdir,
             const float* __restrict__ Tsi, float* __restrict__ dsort,
             const ushort_t* __restrict__ pk,
             const float* __restrict__ b_in, const float* __restrict__ bzv,
             const float* __restrict__ b0v, const float* __restrict__ b1v,
             const float* __restrict__ b_out,
             float* __restrict__ means, float* __restrict__ stds, float* __restrict__ outbuf)
{
  __shared__ int   sOff[64];
  __shared__ float sW[64][8];
  __shared__ float sPx[64], sPy[64], sPz[64];
  __shared__ float sUx[16], sUy[16], sUz[16], sVx[16], sVy[16], sVz[16];
  __shared__ float sMean[64], sStd[64];
  __shared__ __align__(16) ushort_t zf[16*512];
  __shared__ __align__(16) ushort_t Wb[16*512];

  int tid = threadIdx.x;
  int qbase = blockIdx.x * 64;

  if constexpr (OUTD == 2) {
    if (tid < 16) {
      int gray = (qbase >> 2) + tid;
      float a=camK[0],b=camK[1],c=camK[2],d=camK[3],e=camK[4],f=camK[5],g=camK[6],h=camK[7],i=camK[8];
      float c00 = e*i-f*h, c01 = c*h-b*i, c02 = b*f-c*e;
      float c10 = f*g-d*i, c11 = a*i-c*g, c12 = c*d-a*f;
      float c20 = d*h-e*g, c21 = b*g-a*h, c22 = a*e-b*d;
      float det = a*c00 + b*c10 + c*c20;
      float id = 1.f/det;
      float u = (float)pix[2*gray], v = (float)pix[2*gray+1];
      float dx = (c00*u + c01*v + c02)*id;
      float dy = (c10*u + c11*v + c12)*id;
      float dz = (c20*u + c21*v + c22)*id;
      float n = sqrtf(dx*dx+dy*dy+dz*dz);
      dx/=n; dy/=n; dz/=n;
      sUx[tid]=dx; sUy[tid]=dy; sUz[tid]=dz;
      unit[3*gray]=dx; unit[3*gray+1]=dy; unit[3*gray+2]=dz;
      float vx = Tsi[0]*dx + Tsi[1]*dy + Tsi[2]*dz;
      float vy = Tsi[4]*dx + Tsi[5]*dy + Tsi[6]*dz;
      float vz = Tsi[8]*dx + Tsi[9]*dy + Tsi[10]*dz;
      sVx[tid]=vx; sVy[tid]=vy; sVz[tid]=vz;
      viewdir[3*gray]=vx; viewdir[3*gray+1]=vy; viewdir[3*gray+2]=vz;
    }
  } else {
    if (tid == 0) {
      int ray = blockIdx.x;
      sUx[0]=unit[3*ray]; sUy[0]=unit[3*ray+1]; sUz[0]=unit[3*ray+2];
      sVx[0]=viewdir[3*ray]; sVy[0]=viewdir[3*ray+1]; sVz[0]=viewdir[3*ray+2];
    }
  }
  __syncthreads();

  if (tid < 64) {
    float t, ux, uy, uz;
    if constexpr (OUTD == 2) {
      t = ((float)(tid & 3) + 0.5f) * 25.f;
      int lr = tid >> 2;
      ux = sUx[lr]; uy = sUy[lr]; uz = sUz[lr];
    } else {
      t = dsort[qbase + tid];
      ux = sUx[0]; uy = sUy[0]; uz = sUz[0];
    }
    float wx=ux*t, wy=uy*t, wz=uz*t;
    float px = Tsi[0]*wx + Tsi[1]*wy + Tsi[2]*wz + Tsi[3];
    float py = Tsi[4]*wx + Tsi[5]*wy + Tsi[6]*wz + Tsi[7];
    float pz = Tsi[8]*wx + Tsi[9]*wy + Tsi[10]*wz + Tsi[11];
    sPx[tid]=px; sPy[tid]=py; sPz[tid]=pz;
    float gx = (px + 25.6f)*2.5f;
    float gy = (py + 25.6f)*2.5f;
    float gz = (pz + 2.0f)*2.5f;
    bool inb = (gx>=0.f)&&(gx<=127.f)&&(gy>=0.f)&&(gy<=127.f)&&(gz>=0.f)&&(gz<=15.f);
    gx = fminf(fmaxf(gx,0.f),127.f);
    gy = fminf(fmaxf(gy,0.f),127.f);
    gz = fminf(fmaxf(gz,0.f),15.f);
    int x0 = min(max((int)floorf(gx),0),126);
    int y0 = min(max((int)floorf(gy),0),126);
    int z0 = min(max((int)floorf(gz),0),14);
    float fx = gx-(float)x0, fy = gy-(float)y0, fz = gz-(float)z0;
    float sc = inb ? 1.f : 0.f;
    float ax0 = 1.f-fx, ay0 = 1.f-fy;
    float az0 = (1.f-fz)*sc, az1 = fz*sc;
    float q00 = ax0*ay0, q01 = ax0*fy, q10 = fx*ay0, q11 = fx*fy;
    sW[tid][0] = az0*q00; sW[tid][1] = az0*q01; sW[tid][2] = az0*q10; sW[tid][3] = az0*q11;
    sW[tid][4] = az1*q00; sW[tid][5] = az1*q01; sW[tid][6] = az1*q10; sW[tid][7] = az1*q11;
    sOff[tid] = mode ? (((z0*128 + x0)*128 + y0)*128)
                     : (z0*2097152 + x0*128 + y0);
  }
  __syncthreads();

  // trilinear gather -> zf in fragment order, 8 channels/thread-iter
  for (int it = 0; it < 4; ++it) {
    int lin = it*256 + tid;
    int p = lin >> 4, cb = lin & 15;
    float4 wA = *(const float4*)&sW[p][0];
    float4 wB = *(const float4*)&sW[p][4];
    float r0=0,r1=0,r2=0,r3=0,r4=0,r5=0,r6=0,r7=0;
    if (mode) {
      const ushort_t* b = vfh + sOff[p] + cb*8;
      uint4 v;
      #define ACC8(PTR, W) \
        v = *(const uint4*)(PTR); \
        r0 += (W)*b2f_lo(v.x); r1 += (W)*b2f_hi(v.x); \
        r2 += (W)*b2f_lo(v.y); r3 += (W)*b2f_hi(v.y); \
        r4 += (W)*b2f_lo(v.z); r5 += (W)*b2f_hi(v.z); \
        r6 += (W)*b2f_lo(v.w); r7 += (W)*b2f_hi(v.w);
      ACC8(b,                     wA.x)
      ACC8(b + 128,               wA.y)
      ACC8(b + 16384,             wA.z)
      ACC8(b + 16384 + 128,       wA.w)
      ACC8(b + 2097152,           wB.x)
      ACC8(b + 2097152 + 128,     wB.y)
      ACC8(b + 2097152 + 16384,   wB.z)
      ACC8(b + 2097152 + 16512,   wB.w)
      #undef ACC8
    } else {
      const float* bsrc = vf0 + sOff[p];
      float rr[8];
      #pragma unroll
      for (int k = 0; k < 8; ++k) {
        const float* bc = bsrc + (size_t)(cb*8 + k)*16384;
        rr[k] = wA.x*bc[0] + wA.y*bc[1] + wA.z*bc[128] + wA.w*bc[129]
              + wB.x*bc[2097152] + wB.y*bc[2097153] + wB.z*bc[2097280] + wB.w*bc[2097281];
      }
      r0=rr[0]; r1=rr[1]; r2=rr[2]; r3=rr[3]; r4=rr[4]; r5=rr[5]; r6=rr[6]; r7=rr[7];
    }
    uint4 o;
    o.x = pack_trunc(r0, r1); o.y = pack_trunc(r2, r3);
    o.z = pack_trunc(r4, r5); o.w = pack_trunc(r6, r7);
    int T = (cb >> 2)*4 + (p >> 4);
    int lanep = (cb & 3)*16 + (p & 15);
    *(uint4*)(zf + T*512 + lanep*8) = o;
  }

  // PE inputs -> Wb in fragment order (k=0..63, dims 42..63 zero)
  {
    int p = tid & 63, dg = tid >> 6;
    float px = sPx[p], py = sPy[p], pz = sPz[p];
    int lr = (OUTD == 2) ? (p >> 2) : 0;
    float vx = sVx[lr], vy = sVy[lr], vz = sVz[lr];
    #pragma unroll 1
    for (int it = 0; it < 16; ++it) {
      int d = it*4 + dg;
      float val = 0.f;
      if (d < 3)      val = (d==0)?px:((d==1)?py:pz);
      else if (d < 39) {
        int s = d - 3; bool isSin = (s < 18); if (!isSin) s -= 18;
        int axis = s/6, fi = s%6;
        float base = (axis==0)?px:((axis==1)?py:pz);
        float arg = base * (float)(1 << fi);
        val = isSin ? __sinf(arg) : __cosf(arg);
      } else if (d < 42) {
        val = (d==39)?vx:((d==40)?vy:vz);
      }
      int addr = (d>>5)*2048 + (p>>4)*512 + (((d>>3)&3)*16 + (p&15))*8 + (d&7);
      Wb[addr] = f2b_fast(val);
    }
  }
  __syncthreads();

  int wave = tid >> 6, lane = tid & 63;
  int l15 = lane & 15, quad = lane >> 4;
  int chalf = wave >> 1, phalf = wave & 1;
  int cbase = chalf*64 + quad*4;

  f32x4 h[4][2];
  #pragma unroll
  for (int i = 0; i < 4; ++i) {
    f32x4 bi = *(const f32x4*)(b_in + cbase + i*16);
    h[i][0] = bi; h[i][1] = bi;
  }
  gemm_frag<2>(Wb, pk, h, chalf, phalf, lane);

  const ushort_t* pkl = pk + 2*4096;
  #pragma unroll 1
  for (int i3 = 0; i3 < 3; ++i3) {
    gemm_frag<4>(zf, pkl + (size_t)(i3*12)*4096, h, chalf, phalf, lane);
    #pragma unroll
    for (int i = 0; i < 4; ++i) {
      f32x4 bz = *(const f32x4*)(bzv + i3*128 + cbase + i*16);
      h[i][0] += bz; h[i][1] += bz;
    }
    __syncthreads();
    store_reluF(Wb, h, chalf, phalf, lane);
    __syncthreads();
    f32x4 net[4][2];
    #pragma unroll
    for (int i = 0; i < 4; ++i) {
      f32x4 c0b = *(const f32x4*)(b0v + i3*128 + cbase + i*16);
      net[i][0] = c0b; net[i][1] = c0b;
    }
    gemm_frag<4>(Wb, pkl + (size_t)(i3*12+4)*4096, net, chalf, phalf, lane);
    __syncthreads();
    store_reluF(Wb, net, chalf, phalf, lane);
    __syncthreads();
    gemm_frag<4>(Wb, pkl + (size_t)(i3*12+8)*4096, h, chalf, phalf, lane);
    #pragma unroll
    for (int i = 0; i < 4; ++i) {
      f32x4 o1b = *(const f32x4*)(b1v + i3*128 + cbase + i*16);
      h[i][0] += o1b; h[i][1] += o1b;
    }
  }
  __syncthreads();
  store_reluF(Wb, h, chalf, phalf, lane);
  __syncthreads();

  // epilogue: one 16x16 MFMA per wave; wave owns points wave*16..+15
  {
    const ushort_t* pkw = pk + 38*4096;
    f32x4 oa = (f32x4){0.f,0.f,0.f,0.f};
    #pragma unroll
    for (int ks = 0; ks < 4; ++ks) {
      short8 w = *(const short8*)(pkw + (size_t)(ks*64 + lane)*8);
      short8 b = *(const short8*)(Wb + (ks*4 + wave)*512 + lane*8);
      oa = __builtin_amdgcn_mfma_f32_16x16x32_bf16(w, b, oa, 0,0,0);
    }
    if (quad == 0) {
      int lq = wave*16 + l15;
      int q = qbase + lq;
      if constexpr (OUTD == 4) {
        float4 o = { oa[0] + b_out[0], oa[1] + b_out[1], oa[2] + b_out[2], oa[3] + b_out[3] };
        *(float4*)(outbuf + (size_t)q*4) = o;
      } else {
        int g = q & 3;
        float m = fminf(fmaxf(((float)g + 0.5f)*25.f + oa[0] + b_out[0], 0.5f), 100.f);
        float sd = 2.5f*sigmoid_(oa[1] + b_out[1]) + 0.1f;
        means[q] = m; stds[q] = sd;
        sMean[lq] = m; sStd[lq] = sd;
      }
    }
  }

  // gauss: fused depth-set build + rank-sort (16 rays/block)
  if constexpr (OUTD == 2) {
    __syncthreads();
    float* fbuf = (float*)zf;
    int lr = tid >> 4;
    int sbase = (tid & 15) * 4;
    float vals[4];
    #pragma unroll
    for (int t = 0; t < 4; ++t) {
      int slot = sbase + t;
      float val;
      if (slot < 32) val = 0.5f + (float)slot * (99.5f/31.f);
      else {
        int idx = slot - 32, g = idx >> 3, s = idx & 7;
        int lq = lr*4 + g;
        float mu = sMean[lq], sd = sStd[lq];
        val = fminf(fmaxf(mu + sd*noise[(size_t)(qbase + lq)*8 + s], 0.5f), 100.f);
      }
      fbuf[lr*64 + slot] = val;
      vals[t] = val;
    }
    __syncthreads();
    int rk[4] = {0,0,0,0};
    for (int k = 0; k < 64; ++k) {
      float o = fbuf[lr*64 + k];
      #pragma unroll
      for (int t = 0; t < 4; ++t)
        rk[t] += (o < vals[t]) || (o == vals[t] && k < sbase + t);
    }
    int gray = (qbase >> 2) + lr;
    #pragma unroll
    for (int t = 0; t < 4; ++t)
      dsort[(size_t)gray*64 + rk[t]] = vals[t];
  }
}

// ---------- render + losses: one wave per ray, atomic total ----------
__device__ __forceinline__ void bilin3(const float* __restrict__ img, float u, float v, float* out){
  u = fminf(fmaxf(u, 0.f), (float)(WIMG-1));
  v = fminf(fmaxf(v, 0.f), (float)(HIMG-1));
  int u0 = min(max((int)floorf(u),0), WIMG-2);
  int v0 = min(max((int)floorf(v),0), HIMG-2);
  float fu = u - (float)u0, fv = v - (float)v0;
  float w00=(1.f-fv)*(1.f-fu), w01=(1.f-fv)*fu, w10=fv*(1.f-fu), w11=fv*fu;
  #pragma unroll
  for (int c = 0; c < 3; ++c) {
    const float* b = img + (size_t)c*(HIMG*WIMG) + (size_t)v0*WIMG + u0;
    out[c] = w00*b[0] + w01*b[1] + w10*b[WIMG] + w11*b[WIMG+1];
  }
}

__global__ void k_render(const float* __restrict__ outbuf, const float* __restrict__ dsort,
                         const float* __restrict__ means, const float* __restrict__ stds,
                         const float* __restrict__ unit,
                         const float* __restrict__ img_src, const float* __restrict__ img_tgt,
                         const int* __restrict__ pix, const float* __restrict__ camK,
                         const float* __restrict__ Tst, float* __restrict__ loss_out, int R){
  __shared__ float accw[4];
  int gid = blockIdx.x*blockDim.x + threadIdx.x;
  int r = gid >> 6, lane = gid & 63;
  float d = dsort[(size_t)r*64 + lane];
  float dn = __shfl_down(d, 1);
  float delta = (lane < 63) ? (dn - d) : 1e10f;
  float4 o = *(const float4*)(outbuf + (size_t)r*256 + lane*4);
  float sig = softplus_(o.x);
  float alpha = 1.f - __expf(-sig*delta);
  float om = 1.f - alpha + 1e-10f;
  float prod = om;
  #pragma unroll
  for (int off = 1; off < 64; off <<= 1) {
    float v = __shfl_up(prod, off);
    if (lane >= off) prod *= v;
  }
  float texc = __shfl_up(prod, 1);
  if (lane == 0) texc = 1.f;
  float w = alpha * texc;
  float m0=means[r*4],m1=means[r*4+1],m2=means[r*4+2],m3=means[r*4+3];
  float s0=stds[r*4], s1=stds[r*4+1], s2=stds[r*4+2], s3=stds[r*4+3];
  float t0=(d-m0)/s0, t1=(d-m1)/s1, t2=(d-m2)/s2, t3=(d-m3)/s3;
  float pm = 0.25f*0.3989422804014327f*(__expf(-0.5f*t0*t0)/s0 + __expf(-0.5f*t1*t1)/s1
                                      + __expf(-0.5f*t2*t2)/s2 + __expf(-0.5f*t3*t3)/s3);
  float kl  = w * (-__logf(pm + 1e-6f));
  float dep = w * d;
  float c0 = w * sigmoid_(o.y);
  float c1 = w * sigmoid_(o.z);
  float c2 = w * sigmoid_(o.w);
  #pragma unroll
  for (int off = 32; off; off >>= 1) {
    dep += __shfl_xor(dep, off);
    c0  += __shfl_xor(c0, off);
    c1  += __shfl_xor(c1, off);
    c2  += __shfl_xor(c2, off);
    kl  += __shfl_xor(kl, off);
  }
  if (lane == 0) {
    float ld = fminf(fminf(fabsf(m0-dep),fabsf(m1-dep)), fminf(fabsf(m2-dep),fabsf(m3-dep)));
    float src[3], tgt[3];
    float u = (float)pix[2*r], v = (float)pix[2*r+1];
    bilin3(img_src, u, v, src);
    float ux=unit[3*r],uy=unit[3*r+1],uz=unit[3*r+2];
    float pcx=ux*dep, pcy=uy*dep, pcz=uz*dep;
    float ptx = Tst[0]*pcx + Tst[1]*pcy + Tst[2]*pcz + Tst[3];
    float pty = Tst[4]*pcx + Tst[5]*pcy + Tst[6]*pcz + Tst[7];
    float ptz = Tst[8]*pcx + Tst[9]*pcy + Tst[10]*pcz + Tst[11];
    float prx = camK[0]*ptx + camK[1]*pty + camK[2]*ptz;
    float pry = camK[3]*ptx + camK[4]*pty + camK[5]*ptz;
    float prz = camK[6]*ptx + camK[7]*pty + camK[8]*ptz;
    prz = fmaxf(prz, 0.001f);
    bilin3(img_tgt, prx/prz, pry/prz, tgt);
    float lrepr = fabsf(src[0]-tgt[0])+fabsf(src[1]-tgt[1])+fabsf(src[2]-tgt[2]);
    float lcol  = fabsf(src[0]-c0)+fabsf(src[1]-c1)+fabsf(src[2]-c2);
    float invR = 1.f/(float)R;
    accw[threadIdx.x >> 6] = (lrepr + lcol) * (invR/3.f) + kl*invR + 0.01f*ld*invR;
  }
  __syncthreads();
  if (threadIdx.x == 0)
    atomicAdd(loss_out, accw[0]+accw[1]+accw[2]+accw[3]);
}

extern "C" void kernel_launch(void* const* d_in, const int* in_sizes, int n_in,
                              void* d_out, int out_size, void* d_ws, size_t ws_size,
                              hipStream_t stream)
{
  const float* bev   = (const float*)d_in[0];
  const float* camK  = (const float*)d_in[1];
  const float* img_s = (const float*)d_in[2];
  const float* img_t = (const float*)d_in[3];
  const float* Tsi   = (const float*)d_in[4];
  const float* Tst   = (const float*)d_in[5];
  const float* noise = (const float*)d_in[6];
  const int*   pix   = (const int*)d_in[7];
  const float* m_w_in=(const float*)d_in[8];  const float* m_b_in=(const float*)d_in[9];
  const float* m_wz  =(const float*)d_in[10]; const float* m_bz  =(const float*)d_in[11];
  const float* m_w0  =(const float*)d_in[12]; const float* m_b0  =(const float*)d_in[13];
  const float* m_w1  =(const float*)d_in[14]; const float* m_b1  =(const float*)d_in[15];
  const float* m_wo  =(const float*)d_in[16]; const float* m_bo  =(const float*)d_in[17];
  const float* g_w_in=(const float*)d_in[18]; const float* g_b_in=(const float*)d_in[19];
  const float* g_wz  =(const float*)d_in[20]; const float* g_bz  =(const float*)d_in[21];
  const float* g_w0  =(const float*)d_in[22]; const float* g_b0  =(const float*)d_in[23];
  const float* g_w1  =(const float*)d_in[24]; const float* g_b1  =(const float*)d_in[25];
  const float* g_wo  =(const float*)d_in[26]; const float* g_bo  =(const float*)d_in[27];

  int R = in_sizes[7] / 2;
  float* ws = (float*)d_ws;
  size_t off = 0;
  float* unitb = ws + off; off += (size_t)R*3;
  float* vdirb = ws + off; off += (size_t)R*3;
  float* means = ws + off; off += (size_t)R*4;
  float* stds  = ws + off; off += (size_t)R*4;
  float* dsort = ws + off; off += (size_t)R*64;
  float* outbf = ws + off; off += (size_t)R*256;
  ushort_t* pkM = (ushort_t*)(ws + off);
  ushort_t* pkG = pkM + 39*4096;
  off += 39*4096 + 64;
  off = (off + 63) & ~(size_t)63;
  ushort_t* vfh = (ushort_t*)(ws + off);
  size_t need = off*4ull + (size_t)16*128*128*128*2ull;
  int mode = (ws_size >= need) ? 1 : 0;

  k_pack<<<624,256,0,stream>>>(m_w_in, m_wz, m_w0, m_w1, m_wo, 4, pkM, (float*)d_out);
  k_pack<<<624,256,0,stream>>>(g_w_in, g_wz, g_w0, g_w1, g_wo, 2, pkG, nullptr);
  if (mode) {
    dim3 g(2,2,2048);
    k_transpose<<<g,256,0,stream>>>(bev, vfh);
  }
  k_fused<2><<<R/16,256,0,stream>>>(vfh,bev,mode,camK,pix,noise,unitb,vdirb,Tsi,dsort,pkG,
      g_b_in,g_bz,g_b0,g_b1,g_bo, means,stds,nullptr);
  k_fused<4><<<R,256,0,stream>>>(vfh,bev,mode,camK,pix,noise,unitb,vdirb,Tsi,dsort,pkM,
      m_b_in,m_bz,m_b0,m_b1,m_bo, means,stds,outbf);
  k_render<<<R/4,256,0,stream>>>(outbf,dsort,means,stds,unitb,img_s,img_t,pix,camK,Tst,
                                 (float*)d_out,R);
}

// Round 7
// 443.130 us; speedup vs baseline: 1.1981x; 1.1981x over previous
//
#include <hip/hip_runtime.h>

typedef __attribute__((ext_vector_type(8))) short short8;
typedef __attribute__((ext_vector_type(4))) float f32x4;
typedef __attribute__((ext_vector_type(2))) float f32x2;
typedef __attribute__((ext_vector_type(2))) unsigned u32x2;
typedef unsigned short ushort_t;

#define WIMG 1216
#define HIMG 352

__device__ __forceinline__ float sigmoid_(float x){ return 1.f/(1.f+__expf(-x)); }
__device__ __forceinline__ float softplus_(float x){
  return fmaxf(x,0.f) + log1pf(__expf(-fabsf(x)));
}
__device__ __forceinline__ ushort_t f2b(float x){
  union { float f; unsigned u; } v; v.f = x;
  unsigned r = v.u + 0x7FFF + ((v.u >> 16) & 1);
  return (ushort_t)(r >> 16);
}
__device__ __forceinline__ ushort_t f2b_fast(float x){
  union { float f; unsigned u; } v; v.f = x;
  return (ushort_t)((v.u + 0x8000u) >> 16);
}
__device__ __forceinline__ unsigned pack_trunc(float a, float b){
  union { float f; unsigned u; } va, vb; va.f = a; vb.f = b;
  return (va.u >> 16) | (vb.u & 0xFFFF0000u);
}
__device__ __forceinline__ f32x2 bf2x(unsigned u){
  union { unsigned uu[2]; f32x2 f; } v;
  v.uu[0] = u << 16; v.uu[1] = u & 0xFFFF0000u;
  return v.f;
}

// ---------- combined prep: transpose (blocks 0..8191) + weight pack (blocks 8192..9439) ----------
// pack layout blocks 0..37: [w_in ks0,ks1][i: wz*4, w0*4, w1*4]*3 ; block 38: w_out 16-col padded
__global__ __launch_bounds__(256)
void k_prep(const float* __restrict__ bev, ushort_t* __restrict__ vfh, int mode,
            const float* __restrict__ mw_in, const float* __restrict__ mwz,
            const float* __restrict__ mw0, const float* __restrict__ mw1,
            const float* __restrict__ mwo,
            const float* __restrict__ gw_in, const float* __restrict__ gwz,
            const float* __restrict__ gw0, const float* __restrict__ gw1,
            const float* __restrict__ gwo,
            ushort_t* __restrict__ pkM, ushort_t* __restrict__ pkG,
            float* __restrict__ out0){
  int bx = blockIdx.x;
  int tid = threadIdx.x;
  if (bx < 8192) {
    if (!mode) return;
    __shared__ float tile[64][65];
    int y0 = (bx & 1) * 64;
    int c0 = ((bx >> 1) & 1) * 64;
    int zx = bx >> 2;
    const float* s = bev + (size_t)(zx >> 7)*2097152 + (size_t)c0*16384 + (size_t)(zx & 127)*128 + y0;
    int r0 = tid >> 4, f4 = tid & 15;
    #pragma unroll
    for (int it = 0; it < 4; ++it) {
      int c = it*16 + r0;
      f32x4 v = __builtin_nontemporal_load((const f32x4*)(s + (size_t)c*16384 + f4*4));
      tile[c][f4*4+0]=v.x; tile[c][f4*4+1]=v.y; tile[c][f4*4+2]=v.z; tile[c][f4*4+3]=v.w;
    }
    __syncthreads();
    ushort_t* d = vfh + ((size_t)zx*128 + y0)*128 + c0;
    #pragma unroll
    for (int it = 0; it < 4; ++it) {
      int y = it*16 + r0;
      u32x2 o;
      o.x = pack_trunc(tile[f4*4+0][y], tile[f4*4+1][y]);
      o.y = pack_trunc(tile[f4*4+2][y], tile[f4*4+3][y]);
      __builtin_nontemporal_store(o, (u32x2*)(d + (size_t)y*128 + f4*4));
    }
    return;
  }
  int pb = bx - 8192;                 // 0..1247 ; 624 per net
  if (pb == 0 && tid == 0) out0[0] = 0.f;
  int net = pb >= 624;                // 0 = M, 1 = G
  const float* w_in = net ? gw_in : mw_in;
  const float* wz   = net ? gwz   : mwz;
  const float* w0   = net ? gw0   : mw0;
  const float* w1   = net ? gw1   : mw1;
  const float* wo   = net ? gwo   : mwo;
  int outd = net ? 2 : 4;
  ushort_t* pk = net ? pkG : pkM;
  int id = (pb - (net ? 624 : 0))*256 + tid;
  if (id >= 39*4096) return;
  int blk = id >> 12;
  int e = id & 4095;
  float val = 0.f;
  if (blk < 38) {
    int nt = e >> 9, lane = (e >> 3) & 63, j = e & 7;
    int kloc = (lane >> 4)*8 + j;
    int n = nt*16 + (lane & 15);
    if (blk < 2) {
      int k = blk*32 + kloc;
      val = (k < 42) ? w_in[k*128 + n] : 0.f;
    } else {
      int g = blk - 2;
      int i = g / 12, r = g % 12, m = r >> 2, ks = r & 3;
      int k = ks*32 + kloc;
      const float* src = (m==0 ? wz : (m==1 ? w0 : w1)) + i*16384;
      val = src[k*128 + n];
    }
  } else if (e < 2048) {
    int ks = e >> 9, lane = (e >> 3) & 63, j = e & 7;
    int k = ks*32 + (lane >> 4)*8 + j;
    int n = lane & 15;
    val = (n < outd) ? wo[k*outd + n] : 0.f;
  }
  pk[id] = f2b(val);
}

// ---------- fragment GEMM, R4 partition: wave owns 32 out-channels, all 64 points ----------
// weights (A) preloaded up-front; acts (B) in LDS fragment order: (ks*4+nt)*512 + lane*8
template<int KS>
__device__ __forceinline__ void gemm_frag(const ushort_t* lds,
                                          const ushort_t* __restrict__ pkW,
                                          f32x4 acc[2][4], int wave, int lane)
{
  short8 w[KS][2];
  #pragma unroll
  for (int ks = 0; ks < KS; ++ks)
    #pragma unroll
    for (int ct = 0; ct < 2; ++ct)
      w[ks][ct] = *(const short8*)(pkW + (size_t)((ks*8 + wave*2 + ct)*64 + lane)*8);
  #pragma unroll
  for (int ks = 0; ks < KS; ++ks) {
    short8 b[4];
    #pragma unroll
    for (int nt = 0; nt < 4; ++nt)
      b[nt] = *(const short8*)(lds + (ks*4 + nt)*512 + lane*8);
    #pragma unroll
    for (int ct = 0; ct < 2; ++ct)
      #pragma unroll
      for (int nt = 0; nt < 4; ++nt)
        acc[ct][nt] = __builtin_amdgcn_mfma_f32_16x16x32_bf16(w[ks][ct], b[nt], acc[ct][nt], 0,0,0);
  }
}

// D: channel c = wave*32 + ct*16 + quad*4 + r ; point p = nt*16 + l15
// fragment-order store: frag = wave*4 + nt ; lane' = (ct*2 + (quad>>1))*16 + l15 ; j = (quad&1)*4
__device__ __forceinline__ void store_reluF(ushort_t* buf, const f32x4 acc[2][4],
                                            int wave, int lane){
  int l15 = lane & 15, quad = lane >> 4;
  int j = (quad & 1)*4;
  #pragma unroll
  for (int ct = 0; ct < 2; ++ct) {
    int lp = (ct*2 + (quad >> 1))*16 + l15;
    #pragma unroll
    for (int nt = 0; nt < 4; ++nt) {
      uint2 o;
      o.x = pack_trunc(fmaxf(acc[ct][nt][0],0.f), fmaxf(acc[ct][nt][1],0.f));
      o.y = pack_trunc(fmaxf(acc[ct][nt][2],0.f), fmaxf(acc[ct][nt][3],0.f));
      *(uint2*)(buf + (wave*4 + nt)*512 + lp*8 + j) = o;
    }
  }
}

// ---------- fused: OUTD=2 gauss (rayinit + MLP + sort), OUTD=4 main (MLP) ----------
template<int OUTD>
__global__ __launch_bounds__(256, 4)
void k_fused(const ushort_t* __restrict__ vfh, const float* __restrict__ vf0, int mode,
             const float* __restrict__ camK, const int* __restrict__ pix,
             const float* __restrict__ noise,
             float* __restrict__ unit, float* __restrict__ viewdir,
             const float* __restrict__ Tsi, float* __restrict__ dsort,
             const ushort_t* __restrict__ pk,
             const float* __restrict__ b_in, const float* __restrict__ bzv,
             const float* __restrict__ b0v, const float* __restrict__ b1v,
             const float* __restrict__ b_out,
             float* __restrict__ means, float* __restrict__ stds, float* __restrict__ outbuf)
{
  __shared__ int   sOff[64];
  __shared__ float sW[64][8];
  __shared__ float sPx[64], sPy[64], sPz[64];
  __shared__ float sUx[16], sUy[16], sUz[16], sVx[16], sVy[16], sVz[16];
  __shared__ float sMean[64], sStd[64];
  __shared__ __align__(16) ushort_t zf[16*512];
  __shared__ __align__(16) ushort_t Wb[16*512];

  int tid = threadIdx.x;
  int qbase = blockIdx.x * 64;

  if constexpr (OUTD == 2) {
    if (tid < 16) {
      int gray = (qbase >> 2) + tid;
      float a=camK[0],b=camK[1],c=camK[2],d=camK[3],e=camK[4],f=camK[5],g=camK[6],h=camK[7],i=camK[8];
      float c00 = e*i-f*h, c01 = c*h-b*i, c02 = b*f-c*e;
      float c10 = f*g-d*i, c11 = a*i-c*g, c12 = c*d-a*f;
      float c20 = d*h-e*g, c21 = b*g-a*h, c22 = a*e-b*d;
      float det = a*c00 + b*c10 + c*c20;
      float id = 1.f/det;
      float u = (float)pix[2*gray], v = (float)pix[2*gray+1];
      float dx = (c00*u + c01*v + c02)*id;
      float dy = (c10*u + c11*v + c12)*id;
      float dz = (c20*u + c21*v + c22)*id;
      float n = sqrtf(dx*dx+dy*dy+dz*dz);
      dx/=n; dy/=n; dz/=n;
      sUx[tid]=dx; sUy[tid]=dy; sUz[tid]=dz;
      unit[3*gray]=dx; unit[3*gray+1]=dy; unit[3*gray+2]=dz;
      float vx = Tsi[0]*dx + Tsi[1]*dy + Tsi[2]*dz;
      float vy = Tsi[4]*dx + Tsi[5]*dy + Tsi[6]*dz;
      float vz = Tsi[8]*dx + Tsi[9]*dy + Tsi[10]*dz;
      sVx[tid]=vx; sVy[tid]=vy; sVz[tid]=vz;
      viewdir[3*gray]=vx; viewdir[3*gray+1]=vy; viewdir[3*gray+2]=vz;
    }
  } else {
    if (tid == 0) {
      int ray = blockIdx.x;
      sUx[0]=unit[3*ray]; sUy[0]=unit[3*ray+1]; sUz[0]=unit[3*ray+2];
      sVx[0]=viewdir[3*ray]; sVy[0]=viewdir[3*ray+1]; sVz[0]=viewdir[3*ray+2];
    }
  }
  __syncthreads();

  if (tid < 64) {
    float t, ux, uy, uz;
    if constexpr (OUTD == 2) {
      t = ((float)(tid & 3) + 0.5f) * 25.f;
      int lr = tid >> 2;
      ux = sUx[lr]; uy = sUy[lr]; uz = sUz[lr];
    } else {
      t = dsort[qbase + tid];
      ux = sUx[0]; uy = sUy[0]; uz = sUz[0];
    }
    float wx=ux*t, wy=uy*t, wz=uz*t;
    float px = Tsi[0]*wx + Tsi[1]*wy + Tsi[2]*wz + Tsi[3];
    float py = Tsi[4]*wx + Tsi[5]*wy + Tsi[6]*wz + Tsi[7];
    float pz = Tsi[8]*wx + Tsi[9]*wy + Tsi[10]*wz + Tsi[11];
    sPx[tid]=px; sPy[tid]=py; sPz[tid]=pz;
    float gx = (px + 25.6f)*2.5f;
    float gy = (py + 25.6f)*2.5f;
    float gz = (pz + 2.0f)*2.5f;
    bool inb = (gx>=0.f)&&(gx<=127.f)&&(gy>=0.f)&&(gy<=127.f)&&(gz>=0.f)&&(gz<=15.f);
    gx = fminf(fmaxf(gx,0.f),127.f);
    gy = fminf(fmaxf(gy,0.f),127.f);
    gz = fminf(fmaxf(gz,0.f),15.f);
    int x0 = min(max((int)floorf(gx),0),126);
    int y0 = min(max((int)floorf(gy),0),126);
    int z0 = min(max((int)floorf(gz),0),14);
    float fx = gx-(float)x0, fy = gy-(float)y0, fz = gz-(float)z0;
    float sc = inb ? 1.f : 0.f;
    float ax0 = 1.f-fx, ay0 = 1.f-fy;
    float az0 = (1.f-fz)*sc, az1 = fz*sc;
    float q00 = ax0*ay0, q01 = ax0*fy, q10 = fx*ay0, q11 = fx*fy;
    sW[tid][0] = az0*q00; sW[tid][1] = az0*q01; sW[tid][2] = az0*q10; sW[tid][3] = az0*q11;
    sW[tid][4] = az1*q00; sW[tid][5] = az1*q01; sW[tid][6] = az1*q10; sW[tid][7] = az1*q11;
    sOff[tid] = mode ? (((z0*128 + x0)*128 + y0)*128)
                     : (z0*2097152 + x0*128 + y0);
  }
  __syncthreads();

  // trilinear gather -> zf in fragment order, 8 channels/thread-iter, packed f32x2 math
  for (int it = 0; it < 4; ++it) {
    int lin = it*256 + tid;
    int p = lin >> 4, cb = lin & 15;
    float4 wA = *(const float4*)&sW[p][0];
    float4 wB = *(const float4*)&sW[p][4];
    f32x2 r01={0.f,0.f}, r23={0.f,0.f}, r45={0.f,0.f}, r67={0.f,0.f};
    if (mode) {
      const ushort_t* b = vfh + sOff[p] + cb*8;
      uint4 v;
      #define ACC8(PTR, W) \
        v = *(const uint4*)(PTR); \
        r01 += (W)*bf2x(v.x); r23 += (W)*bf2x(v.y); \
        r45 += (W)*bf2x(v.z); r67 += (W)*bf2x(v.w);
      ACC8(b,                     wA.x)
      ACC8(b + 128,               wA.y)
      ACC8(b + 16384,             wA.z)
      ACC8(b + 16384 + 128,       wA.w)
      ACC8(b + 2097152,           wB.x)
      ACC8(b + 2097152 + 128,     wB.y)
      ACC8(b + 2097152 + 16384,   wB.z)
      ACC8(b + 2097152 + 16512,   wB.w)
      #undef ACC8
    } else {
      const float* bsrc = vf0 + sOff[p];
      float rr[8];
      #pragma unroll
      for (int k = 0; k < 8; ++k) {
        const float* bc = bsrc + (size_t)(cb*8 + k)*16384;
        rr[k] = wA.x*bc[0] + wA.y*bc[1] + wA.z*bc[128] + wA.w*bc[129]
              + wB.x*bc[2097152] + wB.y*bc[2097153] + wB.z*bc[2097280] + wB.w*bc[2097281];
      }
      r01 = (f32x2){rr[0],rr[1]}; r23 = (f32x2){rr[2],rr[3]};
      r45 = (f32x2){rr[4],rr[5]}; r67 = (f32x2){rr[6],rr[7]};
    }
    uint4 o;
    o.x = pack_trunc(r01.x, r01.y); o.y = pack_trunc(r23.x, r23.y);
    o.z = pack_trunc(r45.x, r45.y); o.w = pack_trunc(r67.x, r67.y);
    int T = (cb >> 2)*4 + (p >> 4);
    int lanep = (cb & 3)*16 + (p & 15);
    *(uint4*)(zf + T*512 + lanep*8) = o;
  }

  // PE inputs -> Wb in fragment order (k=0..63, dims 42..63 zero)
  {
    int p = tid & 63, dg = tid >> 6;
    float px = sPx[p], py = sPy[p], pz = sPz[p];
    int lr = (OUTD == 2) ? (p >> 2) : 0;
    float vx = sVx[lr], vy = sVy[lr], vz = sVz[lr];
    #pragma unroll 1
    for (int it = 0; it < 16; ++it) {
      int d = it*4 + dg;
      float val = 0.f;
      if (d < 3)      val = (d==0)?px:((d==1)?py:pz);
      else if (d < 39) {
        int s = d - 3; bool isSin = (s < 18); if (!isSin) s -= 18;
        int axis = s/6, fi = s%6;
        float base = (axis==0)?px:((axis==1)?py:pz);
        float arg = base * (float)(1 << fi);
        val = isSin ? __sinf(arg) : __cosf(arg);
      } else if (d < 42) {
        val = (d==39)?vx:((d==40)?vy:vz);
      }
      int addr = (d>>5)*2048 + (p>>4)*512 + (((d>>3)&3)*16 + (p&15))*8 + (d&7);
      Wb[addr] = f2b_fast(val);
    }
  }
  __syncthreads();

  int wave = tid >> 6, lane = tid & 63;
  int l15 = lane & 15, quad = lane >> 4;
  int cbase = wave*32 + quad*4;       // channel base for ct=0 (ct=1 adds 16)

  f32x4 h[2][4];
  #pragma unroll
  for (int ct = 0; ct < 2; ++ct) {
    f32x4 bi = *(const f32x4*)(b_in + cbase + ct*16);
    #pragma unroll
    for (int nt = 0; nt < 4; ++nt) h[ct][nt] = bi;
  }
  gemm_frag<2>(Wb, pk, h, wave, lane);

  const ushort_t* pkl = pk + 2*4096;
  #pragma unroll 1
  for (int i3 = 0; i3 < 3; ++i3) {
    gemm_frag<4>(zf, pkl + (size_t)(i3*12)*4096, h, wave, lane);
    #pragma unroll
    for (int ct = 0; ct < 2; ++ct) {
      f32x4 bz = *(const f32x4*)(bzv + i3*128 + cbase + ct*16);
      #pragma unroll
      for (int nt = 0; nt < 4; ++nt) h[ct][nt] += bz;
    }
    __syncthreads();
    store_reluF(Wb, h, wave, lane);
    __syncthreads();
    f32x4 net[2][4];
    #pragma unroll
    for (int ct = 0; ct < 2; ++ct) {
      f32x4 c0b = *(const f32x4*)(b0v + i3*128 + cbase + ct*16);
      #pragma unroll
      for (int nt = 0; nt < 4; ++nt) net[ct][nt] = c0b;
    }
    gemm_frag<4>(Wb, pkl + (size_t)(i3*12+4)*4096, net, wave, lane);
    __syncthreads();
    store_reluF(Wb, net, wave, lane);
    __syncthreads();
    gemm_frag<4>(Wb, pkl + (size_t)(i3*12+8)*4096, h, wave, lane);
    #pragma unroll
    for (int ct = 0; ct < 2; ++ct) {
      f32x4 o1b = *(const f32x4*)(b1v + i3*128 + cbase + ct*16);
      #pragma unroll
      for (int nt = 0; nt < 4; ++nt) h[ct][nt] += o1b;
    }
  }
  __syncthreads();
  store_reluF(Wb, h, wave, lane);
  __syncthreads();

  // epilogue: one 16x16 MFMA per wave; wave owns points wave*16..+15
  {
    const ushort_t* pkw = pk + 38*4096;
    f32x4 oa = (f32x4){0.f,0.f,0.f,0.f};
    #pragma unroll
    for (int ks = 0; ks < 4; ++ks) {
      short8 w = *(const short8*)(pkw + (size_t)(ks*64 + lane)*8);
      short8 b = *(const short8*)(Wb + (ks*4 + wave)*512 + lane*8);
      oa = __builtin_amdgcn_mfma_f32_16x16x32_bf16(w, b, oa, 0,0,0);
    }
    if (quad == 0) {
      int lq = wave*16 + l15;
      int q = qbase + lq;
      if constexpr (OUTD == 4) {
        float4 o = { oa[0] + b_out[0], oa[1] + b_out[1], oa[2] + b_out[2], oa[3] + b_out[3] };
        *(float4*)(outbuf + (size_t)q*4) = o;
      } else {
        int g = q & 3;
        float m = fminf(fmaxf(((float)g + 0.5f)*25.f + oa[0] + b_out[0], 0.5f), 100.f);
        float sd = 2.5f*sigmoid_(oa[1] + b_out[1]) + 0.1f;
        means[q] = m; stds[q] = sd;
        sMean[lq] = m; sStd[lq] = sd;
      }
    }
  }

  // gauss: fused depth-set build + rank-sort (16 rays/block)
  if constexpr (OUTD == 2) {
    __syncthreads();
    float* fbuf = (float*)zf;
    int lr = tid >> 4;
    int sbase = (tid & 15) * 4;
    float vals[4];
    #pragma unroll
    for (int t = 0; t < 4; ++t) {
      int slot = sbase + t;
      float val;
      if (slot < 32) val = 0.5f + (float)slot * (99.5f/31.f);
      else {
        int idx = slot - 32, g = idx >> 3, s = idx & 7;
        int lq = lr*4 + g;
        float mu = sMean[lq], sd = sStd[lq];
        val = fminf(fmaxf(mu + sd*noise[(size_t)(qbase + lq)*8 + s], 0.5f), 100.f);
      }
      fbuf[lr*64 + slot] = val;
      vals[t] = val;
    }
    __syncthreads();
    int rk[4] = {0,0,0,0};
    for (int k = 0; k < 64; ++k) {
      float o = fbuf[lr*64 + k];
      #pragma unroll
      for (int t = 0; t < 4; ++t)
        rk[t] += (o < vals[t]) || (o == vals[t] && k < sbase + t);
    }
    int gray = (qbase >> 2) + lr;
    #pragma unroll
    for (int t = 0; t < 4; ++t)
      dsort[(size_t)gray*64 + rk[t]] = vals[t];
  }
}

// ---------- render + losses: one wave per ray, atomic total ----------
__device__ __forceinline__ void bilin3(const float* __restrict__ img, float u, float v, float* out){
  u = fminf(fmaxf(u, 0.f), (float)(WIMG-1));
  v = fminf(fmaxf(v, 0.f), (float)(HIMG-1));
  int u0 = min(max((int)floorf(u),0), WIMG-2);
  int v0 = min(max((int)floorf(v),0), HIMG-2);
  float fu = u - (float)u0, fv = v - (float)v0;
  float w00=(1.f-fv)*(1.f-fu), w01=(1.f-fv)*fu, w10=fv*(1.f-fu), w11=fv*fu;
  #pragma unroll
  for (int c = 0; c < 3; ++c) {
    const float* b = img + (size_t)c*(HIMG*WIMG) + (size_t)v0*WIMG + u0;
    out[c] = w00*b[0] + w01*b[1] + w10*b[WIMG] + w11*b[WIMG+1];
  }
}

__global__ void k_render(const float* __restrict__ outbuf, const float* __restrict__ dsort,
                         const float* __restrict__ means, const float* __restrict__ stds,
                         const float* __restrict__ unit,
                         const float* __restrict__ img_src, const float* __restrict__ img_tgt,
                         const int* __restrict__ pix, const float* __restrict__ camK,
                         const float* __restrict__ Tst, float* __restrict__ loss_out, int R){
  __shared__ float accw[4];
  int gid = blockIdx.x*blockDim.x + threadIdx.x;
  int r = gid >> 6, lane = gid & 63;
  float d = dsort[(size_t)r*64 + lane];
  float dn = __shfl_down(d, 1);
  float delta = (lane < 63) ? (dn - d) : 1e10f;
  float4 o = *(const float4*)(outbuf + (size_t)r*256 + lane*4);
  float sig = softplus_(o.x);
  float alpha = 1.f - __expf(-sig*delta);
  float om = 1.f - alpha + 1e-10f;
  float prod = om;
  #pragma unroll
  for (int off = 1; off < 64; off <<= 1) {
    float v = __shfl_up(prod, off);
    if (lane >= off) prod *= v;
  }
  float texc = __shfl_up(prod, 1);
  if (lane == 0) texc = 1.f;
  float w = alpha * texc;
  float m0=means[r*4],m1=means[r*4+1],m2=means[r*4+2],m3=means[r*4+3];
  float s0=stds[r*4], s1=stds[r*4+1], s2=stds[r*4+2], s3=stds[r*4+3];
  float t0=(d-m0)/s0, t1=(d-m1)/s1, t2=(d-m2)/s2, t3=(d-m3)/s3;
  float pm = 0.25f*0.3989422804014327f*(__expf(-0.5f*t0*t0)/s0 + __expf(-0.5f*t1*t1)/s1
                                      + __expf(-0.5f*t2*t2)/s2 + __expf(-0.5f*t3*t3)/s3);
  float kl  = w * (-__logf(pm + 1e-6f));
  float dep = w * d;
  float c0 = w * sigmoid_(o.y);
  float c1 = w * sigmoid_(o.z);
  float c2 = w * sigmoid_(o.w);
  #pragma unroll
  for (int off = 32; off; off >>= 1) {
    dep += __shfl_xor(dep, off);
    c0  += __shfl_xor(c0, off);
    c1  += __shfl_xor(c1, off);
    c2  += __shfl_xor(c2, off);
    kl  += __shfl_xor(kl, off);
  }
  if (lane == 0) {
    float ld = fminf(fminf(fabsf(m0-dep),fabsf(m1-dep)), fminf(fabsf(m2-dep),fabsf(m3-dep)));
    float src[3], tgt[3];
    float u = (float)pix[2*r], v = (float)pix[2*r+1];
    bilin3(img_src, u, v, src);
    float ux=unit[3*r],uy=unit[3*r+1],uz=unit[3*r+2];
    float pcx=ux*dep, pcy=uy*dep, pcz=uz*dep;
    float ptx = Tst[0]*pcx + Tst[1]*pcy + Tst[2]*pcz + Tst[3];
    float pty = Tst[4]*pcx + Tst[5]*pcy + Tst[6]*pcz + Tst[7];
    float ptz = Tst[8]*pcx + Tst[9]*pcy + Tst[10]*pcz + Tst[11];
    float prx = camK[0]*ptx + camK[1]*pty + camK[2]*ptz;
    float pry = camK[3]*ptx + camK[4]*pty + camK[5]*ptz;
    float prz = camK[6]*ptx + camK[7]*pty + camK[8]*ptz;
    prz = fmaxf(prz, 0.001f);
    bilin3(img_tgt, prx/prz, pry/prz, tgt);
    float lrepr = fabsf(src[0]-tgt[0])+fabsf(src[1]-tgt[1])+fabsf(src[2]-tgt[2]);
    float lcol  = fabsf(src[0]-c0)+fabsf(src[1]-c1)+fabsf(src[2]-c2);
    float invR = 1.f/(float)R;
    accw[threadIdx.x >> 6] = (lrepr + lcol) * (invR/3.f) + kl*invR + 0.01f*ld*invR;
  }
  __syncthreads();
  if (threadIdx.x == 0)
    atomicAdd(loss_out, accw[0]+accw[1]+accw[2]+accw[3]);
}

extern "C" void kernel_launch(void* const* d_in, const int* in_sizes, int n_in,
                              void* d_out, int out_size, void* d_ws, size_t ws_size,
                              hipStream_t stream)
{
  const float* bev   = (const float*)d_in[0];
  const float* camK  = (const float*)d_in[1];
  const float* img_s = (const float*)d_in[2];
  const float* img_t = (const float*)d_in[3];
  const float* Tsi   = (const float*)d_in[4];
  const float* Tst   = (const float*)d_in[5];
  const float* noise = (const float*)d_in[6];
  const int*   pix   = (const int*)d_in[7];
  const float* m_w_in=(const float*)d_in[8];  const float* m_b_in=(const float*)d_in[9];
  const float* m_wz  =(const float*)d_in[10]; const float* m_bz  =(const float*)d_in[11];
  const float* m_w0  =(const float*)d_in[12]; const float* m_b0  =(const float*)d_in[13];
  const float* m_w1  =(const float*)d_in[14]; const float* m_b1  =(const float*)d_in[15];
  const float* m_wo  =(const float*)d_in[16]; const float* m_bo  =(const float*)d_in[17];
  const float* g_w_in=(const float*)d_in[18]; const float* g_b_in=(const float*)d_in[19];
  const float* g_wz  =(const float*)d_in[20]; const float* g_bz  =(const float*)d_in[21];
  const float* g_w0  =(const float*)d_in[22]; const float* g_b0  =(const float*)d_in[23];
  const float* g_w1  =(const float*)d_in[24]; const float* g_b1  =(const float*)d_in[25];
  const float* g_wo  =(const float*)d_in[26]; const float* g_bo  =(const float*)d_in[27];

  int R = in_sizes[7] / 2;
  float* ws = (float*)d_ws;
  size_t off = 0;
  float* unitb = ws + off; off += (size_t)R*3;
  float* vdirb = ws + off; off += (size_t)R*3;
  float* means = ws + off; off += (size_t)R*4;
  float* stds  = ws + off; off += (size_t)R*4;
  float* dsort = ws + off; off += (size_t)R*64;
  float* outbf = ws + off; off += (size_t)R*256;
  ushort_t* pkM = (ushort_t*)(ws + off);
  ushort_t* pkG = pkM + 39*4096;
  off += 39*4096 + 64;
  off = (off + 63) & ~(size_t)63;
  ushort_t* vfh = (ushort_t*)(ws + off);
  size_t need = off*4ull + (size_t)16*128*128*128*2ull;
  int mode = (ws_size >= need) ? 1 : 0;

  k_prep<<<9440,256,0,stream>>>(bev, vfh, mode,
      m_w_in,m_wz,m_w0,m_w1,m_wo, g_w_in,g_wz,g_w0,g_w1,g_wo,
      pkM, pkG, (float*)d_out);
  k_fused<2><<<R/16,256,0,stream>>>(vfh,bev,mode,camK,pix,noise,unitb,vdirb,Tsi,dsort,pkG,
      g_b_in,g_bz,g_b0,g_b1,g_bo, means,stds,nullptr);
  k_fused<4><<<R,256,0,stream>>>(vfh,bev,mode,camK,pix,noise,unitb,vdirb,Tsi,dsort,pkM,
      m_b_in,m_bz,m_b0,m_b1,m_bo, means,stds,outbf);
  k_render<<<R/4,256,0,stream>>>(outbf,dsort,means,stds,unitb,img_s,img_t,pix,camK,Tst,
                                 (float*)d_out,R);
}